// Round 10
// baseline (223.140 us; speedup 1.0000x reference)
//
#include <hip/hip_runtime.h>
#include <hip/hip_bf16.h>
#include <math.h>

// ---------------------------------------------------------------------------
// MoE gate via fp16 hi/lo split MFMA, 3 products (validated round 5):
//   x = xh + xl/2048,  W*64 = wh + wl/2048
//   logit = ( xh·wh + (xh·wl + xl·wh)/2048 ) / 64
// Round 10: LDS-traffic fix. r8/r9 were LDS-pipe-bound (A+B through LDS >
// MFMA cycles). Now A goes global->reg->convert per wave (fragment load is
// 16x128B coalesced; 4 waves share the 8KB A-chunk via L1), LDS holds only
// B (dbuf 2x32KB -> 2 blocks/CU). BM=64, BN=256 (X HBM-read once), BK=32,
// wave tile 64x64. Counted tile-end vmcnt(8) keeps A-prefetch in flight.
// Numerics / routing / convert_w identical to round 9 (passed).
// ---------------------------------------------------------------------------

typedef _Float16 f16x8 __attribute__((ext_vector_type(8)));
typedef float    f32x4 __attribute__((ext_vector_type(4)));

__device__ __forceinline__ void glds16(const void* g, void* l) {
  __builtin_amdgcn_global_load_lds(
      (const __attribute__((address_space(1))) void*)g,
      (__attribute__((address_space(3))) void*)l, 16, 0, 0);
}

__device__ __forceinline__ unsigned short f2h(float f) {
  _Float16 h = (_Float16)f;                       // v_cvt_f16_f32, RTN
  return __builtin_bit_cast(unsigned short, h);
}
__device__ __forceinline__ float h2f(unsigned short b) {
  return (float)__builtin_bit_cast(_Float16, b);
}

// swizzle for 64B rows (4 granules of 16B), bijective in gi per row.
__device__ __forceinline__ int swz(int gi, int row) {
  return gi ^ (row & 3) ^ ((row >> 2) & 3);
}

// ---------------------------------------------------------------------------
// W [256][7168] fp32 -> Whi/Wlo fp16, tiled pre-swizzled layout (BK=32):
// K-tile t in 0..223 = 256 rows x 32 f16 = 8192 ushorts (16KB).
// element (r,k): gi=k>>3, addr = t*8192 + r*32 + swz(gi,r)*8 + (k&7).
// Whi = fp16(64*W); Wlo = fp16((64*W - Whi) * 2048).   (validated r9)
// ---------------------------------------------------------------------------
__global__ __launch_bounds__(256) void convert_w(
    const float* __restrict__ W,
    unsigned short* __restrict__ Whi, unsigned short* __restrict__ Wlo)
{
  const int e = blockIdx.x;           // expert/row 0..255
  const int t = threadIdx.x;          // 0..255, use 224 (one K-tile each)
  if (t >= 224) return;
  const float* src = W + (size_t)e * 7168 + t * 32;
  const size_t tbase = (size_t)t * 8192 + (size_t)e * 32;
  #pragma unroll
  for (int g = 0; g < 4; ++g) {       // granule gi = g, k = g*8..g*8+7
    unsigned int hw[4], lw[4];
    #pragma unroll
    for (int p = 0; p < 4; ++p) {
      float f0 = src[g * 8 + 2 * p] * 64.0f;
      float f1 = src[g * 8 + 2 * p + 1] * 64.0f;
      unsigned short h0 = f2h(f0), h1 = f2h(f1);
      unsigned short l0 = f2h((f0 - h2f(h0)) * 2048.0f);
      unsigned short l1 = f2h((f1 - h2f(h1)) * 2048.0f);
      hw[p] = (unsigned)h0 | ((unsigned)h1 << 16);
      lw[p] = (unsigned)l0 | ((unsigned)l1 << 16);
    }
    const size_t base = tbase + (size_t)(swz(g, e) * 8);
    *(uint4*)(Whi + base) = make_uint4(hw[0], hw[1], hw[2], hw[3]);
    *(uint4*)(Wlo + base) = make_uint4(lw[0], lw[1], lw[2], lw[3]);
  }
}

// fp32x8 -> (hi f16x8, lo f16x8) packed
__device__ __forceinline__ void conv_frag(const float4& a0, const float4& a1,
                                          f16x8& hv, f16x8& lv) {
  float ff[8] = {a0.x, a0.y, a0.z, a0.w, a1.x, a1.y, a1.z, a1.w};
  unsigned int hw[4], lw[4];
  #pragma unroll
  for (int q = 0; q < 4; ++q) {
    float f0 = ff[2 * q], f1 = ff[2 * q + 1];
    unsigned short h0 = f2h(f0), h1 = f2h(f1);
    unsigned short l0 = f2h((f0 - h2f(h0)) * 2048.0f);
    unsigned short l1 = f2h((f1 - h2f(h1)) * 2048.0f);
    hw[q] = (unsigned)h0 | ((unsigned)h1 << 16);
    lw[q] = (unsigned)l0 | ((unsigned)l1 << 16);
  }
  uint4 h4 = make_uint4(hw[0], hw[1], hw[2], hw[3]);
  uint4 l4 = make_uint4(lw[0], lw[1], lw[2], lw[3]);
  hv = __builtin_bit_cast(f16x8, h4);
  lv = __builtin_bit_cast(f16x8, l4);
}

// ---------------------------------------------------------------------------
// GEMM: BM=64, BN=256, BK=32, K-split KS. 256 threads = 4 waves (1x4),
// wave tile 64x64 = 4x4 frags of 16x16x32 f16 MFMA, 3 products.
// A: per-wave global->reg->convert (no LDS). B: glds into dbuf LDS
// (2x32KB). Per tile: convert A(s) -> issue glds B(s+1) -> issue A(s+1)
// loads -> ds_read B(s) -> 48 MFMA -> vmcnt(8) (A prefetch stays in
// flight) -> barrier.
// ---------------------------------------------------------------------------
__global__ __launch_bounds__(256, 2) void gate_gemm(
    const float* __restrict__ X,
    const unsigned short* __restrict__ Whi,
    const unsigned short* __restrict__ Wlo,
    float* __restrict__ Spart, int D, int TILES, int KS)
{
  __shared__ char lds[65536];
  // buffer b at b*32768: Bhi +0 (16KB, 256 rows x 64B), Blo +16384

  const int bid = blockIdx.x;
  const int ks = bid % KS;              // XCD-affine for KS=8
  const int bm = bid / KS;
  const int tid = threadIdx.x, lane = tid & 63, wid = tid >> 6;
  const int TM = bm * 64;
  const int k0base = ks * TILES * 32;
  const int gi = lane >> 4;

  // A: lane reads row TM + m*16 + (lane&15), k = gi*8.. (8 fp32 = 2 float4)
  const float* xbase = X + (size_t)(TM + (lane & 15)) * D + k0base + gi * 8;
  const size_t mstride = (size_t)16 * D;

  const unsigned short* wh_tile = Whi + (size_t)(ks * TILES) * 8192;
  const unsigned short* wl_tile = Wlo + (size_t)(ks * TILES) * 8192;

  f32x4 acc1[4][4], acc2[4][4];
  #pragma unroll
  for (int m = 0; m < 4; ++m)
    #pragma unroll
    for (int n = 0; n < 4; ++n) { acc1[m][n] = (f32x4)0.0f; acc2[m][n] = (f32x4)0.0f; }

  // B fragment read byte offsets, fixed per lane
  int bro[4];
  #pragma unroll
  for (int n = 0; n < 4; ++n) {
    const int row = wid * 64 + n * 16 + (lane & 15);
    bro[n] = row * 64 + swz(gi, row) * 16;
  }

  // ---- prologue: stage B(0) into buf0; load A(0) ----
  float4 pa[8];
  #pragma unroll
  for (int i = 0; i < 4; ++i) {
    const int c = wid * 4 + i;          // chunk 0..15, wave-uniform
    glds16(wh_tile + c * 512 + lane * 8, lds + c * 1024);
    glds16(wl_tile + c * 512 + lane * 8, lds + 16384 + c * 1024);
  }
  #pragma unroll
  for (int m = 0; m < 4; ++m) {
    pa[2 * m]     = *(const float4*)(xbase + m * mstride);
    pa[2 * m + 1] = *(const float4*)(xbase + m * mstride + 4);
  }
  asm volatile("s_waitcnt vmcnt(8)" ::: "memory");   // B(0) staged; A(0) in flight
  __builtin_amdgcn_sched_barrier(0);
  __builtin_amdgcn_s_barrier();

  int cur = 0;
  for (int s = 0; s < TILES; ++s) {
    char* base_c = lds + cur * 32768;
    char* base_n = lds + (cur ^ 1) * 32768;
    const bool stage_next = (s + 1 < TILES);

    // 1. convert A(s) (compiler waits the pa loads; glds not yet issued)
    f16x8 ah[4], al[4];
    #pragma unroll
    for (int m = 0; m < 4; ++m)
      conv_frag(pa[2 * m], pa[2 * m + 1], ah[m], al[m]);

    // 2. issue glds B(s+1) (oldest vmem in this tile)
    if (stage_next) {
      const unsigned short* wh = wh_tile + (size_t)(s + 1) * 8192;
      const unsigned short* wl = wl_tile + (size_t)(s + 1) * 8192;
      #pragma unroll
      for (int i = 0; i < 4; ++i) {
        const int c = wid * 4 + i;
        glds16(wh + c * 512 + lane * 8, base_n + c * 1024);
        glds16(wl + c * 512 + lane * 8, base_n + 16384 + c * 1024);
      }
    }
    __builtin_amdgcn_sched_barrier(0);

    // 3. issue A(s+1) loads (stay in flight across the barrier)
    {
      const int sn = stage_next ? (s + 1) : s;
      #pragma unroll
      for (int m = 0; m < 4; ++m) {
        pa[2 * m]     = *(const float4*)(xbase + m * mstride + (size_t)sn * 32);
        pa[2 * m + 1] = *(const float4*)(xbase + m * mstride + (size_t)sn * 32 + 4);
      }
    }
    __builtin_amdgcn_sched_barrier(0);

    // 4. ds_read B(s) fragments; 5. MFMA
    {
      f16x8 bh[4], bl[4];
      #pragma unroll
      for (int n = 0; n < 4; ++n) {
        bh[n] = *(const f16x8*)(base_c + bro[n]);
        bl[n] = *(const f16x8*)(base_c + 16384 + bro[n]);
      }
      __builtin_amdgcn_s_setprio(1);
      #pragma unroll
      for (int m = 0; m < 4; ++m)
        #pragma unroll
        for (int n = 0; n < 4; ++n) {
          acc1[m][n] = __builtin_amdgcn_mfma_f32_16x16x32_f16(ah[m], bh[n], acc1[m][n], 0, 0, 0);
          acc2[m][n] = __builtin_amdgcn_mfma_f32_16x16x32_f16(ah[m], bl[n], acc2[m][n], 0, 0, 0);
          acc2[m][n] = __builtin_amdgcn_mfma_f32_16x16x32_f16(al[m], bh[n], acc2[m][n], 0, 0, 0);
        }
      __builtin_amdgcn_s_setprio(0);
    }

    // 6. counted drain: glds B(s+1) (8, oldest) done; 8 A loads stay in flight
    asm volatile("s_waitcnt vmcnt(8)" ::: "memory");
    __builtin_amdgcn_sched_barrier(0);
    __builtin_amdgcn_s_barrier();

    cur ^= 1;
  }

  // epilogue: logit partial = (acc1 + acc2/2048) / 64
  // C/D layout: col=lane&15, row=(lane>>4)*4+reg
  float* Sp = Spart + (size_t)ks * 8192 * 256;
  #pragma unroll
  for (int m = 0; m < 4; ++m)
    #pragma unroll
    for (int n = 0; n < 4; ++n)
      #pragma unroll
      for (int r = 0; r < 4; ++r) {
        const int t = TM + m * 16 + (lane >> 4) * 4 + r;
        const int e = wid * 64 + n * 16 + (lane & 15);
        Sp[(size_t)t * 256 + e] =
            (acc1[m][n][r] + acc2[m][n][r] * (1.0f / 2048.0f)) * (1.0f / 64.0f);
      }
}

// ---------------------------------------------------------------------------
// Routing: one wave per token. logit = sum of KS fp32 partials in DOUBLE
// (exact); scores = sigmoid (fp32); then grouped top-k (8 groups, top-2
// group score, top-4 groups, top-8 experts, renorm * 2.5).
// ---------------------------------------------------------------------------
__global__ __launch_bounds__(256) void gate_routing(
    const float* __restrict__ Spart, int KS,
    const float* __restrict__ bias,
    float* __restrict__ outw, float* __restrict__ outi, int T)
{
  const int lane = threadIdx.x & 63;
  const int wave = threadIdx.x >> 6;
  const int t = blockIdx.x * 4 + wave;
  if (t >= T) return;

  double l[4] = {0.0, 0.0, 0.0, 0.0};
  for (int ks = 0; ks < KS; ++ks) {
    float4 p = *(const float4*)(Spart + (size_t)ks * T * 256
                                + (size_t)t * 256 + lane * 4);
    l[0] += (double)p.x; l[1] += (double)p.y;
    l[2] += (double)p.z; l[3] += (double)p.w;
  }

  float4 bi = *(const float4*)(bias + lane * 4);
  float orig[4], s[4];
  #pragma unroll
  for (int u = 0; u < 4; ++u)
    orig[u] = 1.0f / (1.0f + expf(-(float)l[u]));
  s[0] = orig[0] + bi.x; s[1] = orig[1] + bi.y;
  s[2] = orig[2] + bi.z; s[3] = orig[3] + bi.w;

  // per-lane top-2 of its 4 biased scores
  float m1 = -INFINITY, m2 = -INFINITY;
  #pragma unroll
  for (int u = 0; u < 4; ++u) {
    float v = s[u];
    if (v > m1) { m2 = m1; m1 = v; }
    else if (v > m2) { m2 = v; }
  }
  // merge top-2 across the 8 lanes of the group
  #pragma unroll
  for (int off = 1; off < 8; off <<= 1) {
    float o1 = __shfl_xor(m1, off, 64);
    float o2 = __shfl_xor(m2, off, 64);
    if (o1 > m1) { m2 = fmaxf(m1, o2); m1 = o1; }
    else         { m2 = fmaxf(m2, o1); }
  }
  const float gscore = m1 + m2;

  const int g = lane >> 3;
  int rank = 0;
  #pragma unroll
  for (int j = 0; j < 8; ++j) {
    float gs = __shfl(gscore, j * 8, 64);
    rank += (gs > gscore || (gs == gscore && j < g)) ? 1 : 0;
  }
  if (rank >= 4) { s[0] = s[1] = s[2] = s[3] = -INFINITY; }

  float wsum = 0.0f, sel_w = 0.0f;
  int sel_i = 0;
  #pragma unroll
  for (int it = 0; it < 8; ++it) {
    float bv = s[0]; int bu = 0;
    #pragma unroll
    for (int u = 1; u < 4; ++u)
      if (s[u] > bv) { bv = s[u]; bu = u; }
    float v = bv;
    int ix = lane * 4 + bu;
    float og = orig[bu];
    #pragma unroll
    for (int off = 1; off < 64; off <<= 1) {
      float ov  = __shfl_xor(v,  off, 64);
      int   oix = __shfl_xor(ix, off, 64);
      float oog = __shfl_xor(og, off, 64);
      if (ov > v || (ov == v && oix < ix)) { v = ov; ix = oix; og = oog; }
    }
    if (lane == it) { sel_w = og; sel_i = ix; }
    wsum += og;
    if ((ix >> 2) == lane) s[ix & 3] = -INFINITY;
  }

  if (lane < 8) {
    outw[(size_t)t * 8 + lane] = sel_w / wsum * 2.5f;
    outi[(size_t)t * 8 + lane] = (float)sel_i;
  }
}

extern "C" void kernel_launch(void* const* d_in, const int* in_sizes, int n_in,
                              void* d_out, int out_size, void* d_ws, size_t ws_size,
                              hipStream_t stream) {
  const float* x = (const float*)d_in[0];
  const float* w = (const float*)d_in[1];
  const float* b = (const float*)d_in[2];
  const int E = in_sizes[2];                  // 256
  const int D = in_sizes[1] / E;              // 7168
  const int T = in_sizes[0] / D;              // 8192

  unsigned short* Whi = (unsigned short*)d_ws;                       // 3.67 MB
  unsigned short* Wlo = (unsigned short*)((char*)d_ws + (4u << 20)); // 3.67 MB
  float* Spart = (float*)((char*)d_ws + (8u << 20));                 // KS x 8 MB

  // adaptive K-split: largest of {8,4,2} that fits the workspace
  const size_t per_part = (size_t)T * E * 4;
  int KS = 2;
  if (ws_size >= (8u << 20) + 8 * per_part) KS = 8;
  else if (ws_size >= (8u << 20) + 4 * per_part) KS = 4;
  const int TILES = D / (32 * KS);            // 28 for KS=8

  float* outw = (float*)d_out;
  float* outi = outw + (size_t)T * 8;

  convert_w<<<E, 256, 0, stream>>>(w, Whi, Wlo);
  // grid: (T/64) x KS, ks fastest (XCD-affine for KS=8)
  gate_gemm<<<(T / 64) * KS, 256, 0, stream>>>(x, Whi, Wlo, Spart, D, TILES, KS);
  gate_routing<<<(T + 3) / 4, 256, 0, stream>>>(Spart, KS, b, outw, outi, T);
}

// Round 11
// 147.410 us; speedup vs baseline: 1.5137x; 1.5137x over previous
//
#include <hip/hip_runtime.h>
#include <hip/hip_bf16.h>
#include <math.h>

// ---------------------------------------------------------------------------
// MoE gate via fp16 hi/lo split MFMA, 3 products (validated round 5):
//   x = xh + xl/2048,  W*64 = wh + wl/2048
//   logit = ( xh·wh + (xh·wl + xl·wh)/2048 ) / 64
// Round 11 = round 7 (137us, best) + two surgical fixes:
//  (T4) counted tile-end drain: s_waitcnt vmcnt(4) lgkmcnt(0) + raw
//       s_barrier -- drains the 4 glds for buf[nxt], keeps the 4 A-prefetch
//       HBM loads in flight across the barrier (r7's __syncthreads drained
//       them -> ~1600 dead cyc/tile).
//  (T1) ks = bid % KS XCD-affine decode: per-XCD W working set 896KB ->
//       L2-resident B staging (r7's 3-D grid spread W over all XCDs > L2).
//  (T5) setprio around MFMA cluster (2 independent blocks/CU).
// Numerics / layouts / routing byte-identical to round 7 (passed).
// ---------------------------------------------------------------------------

typedef _Float16 f16x8 __attribute__((ext_vector_type(8)));
typedef float    f32x4 __attribute__((ext_vector_type(4)));

__device__ __forceinline__ void glds16(const void* g, void* l) {
  __builtin_amdgcn_global_load_lds(
      (const __attribute__((address_space(1))) void*)g,
      (__attribute__((address_space(3))) void*)l, 16, 0, 0);
}

__device__ __forceinline__ unsigned short f2h(float f) {
  _Float16 h = (_Float16)f;                       // v_cvt_f16_f32, RTN
  return __builtin_bit_cast(unsigned short, h);
}
__device__ __forceinline__ float h2f(unsigned short b) {
  return (float)__builtin_bit_cast(_Float16, b);
}

// swizzle: 64B rows, 4 granules of 16B; bijective in gi per row.
__device__ __forceinline__ int swz(int gi, int row) {
  return gi ^ (row & 3) ^ ((row >> 2) & 3);
}

// ---------------------------------------------------------------------------
// W [256][7168] fp32 -> Whi/Wlo fp16, tiled pre-swizzled layout (BK=32):
// tile (bn in 0..1, s in 0..223) = 128 rows x 32 f16 = 4096 ushorts (8KB).
// element (r,k): gi=(k&31)>>3, addr = tile*4096 + r*32 + swz(gi,r)*8 + (k&7)
// Whi = fp16(64*W); Wlo = fp16((64*W - Whi) * 2048).
// ---------------------------------------------------------------------------
__global__ __launch_bounds__(256) void convert_w(
    const float* __restrict__ W,
    unsigned short* __restrict__ Whi, unsigned short* __restrict__ Wlo)
{
  const int e = blockIdx.x;           // expert 0..255
  const int t = threadIdx.x;          // 0..255, use 224 (one BK=32 tile each)
  if (t >= 224) return;
  const int r = e & 127, bn = e >> 7;
  const float* src = W + (size_t)e * 7168 + t * 32;
  const size_t tbase = (size_t)(bn * 224 + t) * 4096 + (size_t)r * 32;
  #pragma unroll
  for (int g = 0; g < 4; ++g) {       // granule gi = g, k = g*8..g*8+7
    unsigned int hw[4], lw[4];
    #pragma unroll
    for (int p = 0; p < 4; ++p) {
      float f0 = src[g * 8 + 2 * p] * 64.0f;
      float f1 = src[g * 8 + 2 * p + 1] * 64.0f;
      unsigned short h0 = f2h(f0), h1 = f2h(f1);
      unsigned short l0 = f2h((f0 - h2f(h0)) * 2048.0f);
      unsigned short l1 = f2h((f1 - h2f(h1)) * 2048.0f);
      hw[p] = (unsigned)h0 | ((unsigned)h1 << 16);
      lw[p] = (unsigned)l0 | ((unsigned)l1 << 16);
    }
    const size_t base = tbase + (size_t)(swz(g, r) * 8);
    *(uint4*)(Whi + base) = make_uint4(hw[0], hw[1], hw[2], hw[3]);
    *(uint4*)(Wlo + base) = make_uint4(lw[0], lw[1], lw[2], lw[3]);
  }
}

// ---------------------------------------------------------------------------
// GEMM: BM=128, BN=128, BK=32, K-split KS. 256 threads = 4 waves (2x2),
// wave tile 64x64 = 4x4 frags of 16x16x32 f16 MFMA, 3 products.
// Double-buffered LDS (2 x 32KB). Per iter: issue glds B(s+1) -> issue
// A(s+2) loads (clamped; always 4 in flight) -> compute buf[cur]
// (setprio) -> convert/ds_write A(s+1) -> counted vmcnt(4) + s_barrier.
// Grid 1-D: ks = bid % KS (XCD-affine), bn = (bid/KS)&1, bm = bid/(2KS).
// ---------------------------------------------------------------------------
__global__ __launch_bounds__(256, 2) void gate_gemm(
    const float* __restrict__ X,
    const unsigned short* __restrict__ Whi,
    const unsigned short* __restrict__ Wlo,
    float* __restrict__ Spart, int D, int TILES, int KS)
{
  __shared__ char lds[65536];
  // buffer b at b*32768: Ahi +0 (8KB), Alo +8192, Bhi +16384, Blo +24576

  const int bid = blockIdx.x;
  const int ks = bid % KS;                 // XCD-affine for KS=8
  const int bn = (bid / KS) & 1;
  const int bm = bid / (2 * KS);
  const int tid = threadIdx.x, lane = tid & 63, wid = tid >> 6;
  const int wm = wid >> 1, wn = wid & 1;   // 2x2 wave grid
  const int TM = bm * 128;
  const int k0base = ks * TILES * 32;      // K-chunk start

  // A staging: 2 threads per row, 16 contiguous fp32 each
  const int srow = tid >> 1, skq = tid & 1;
  const float* xsrc = X + (size_t)(TM + srow) * D + k0base + skq * 16;
  const int aw0 = srow * 64 + swz(skq * 2 + 0, srow) * 16;
  const int aw1 = srow * 64 + swz(skq * 2 + 1, srow) * 16;

  const unsigned short* wh_tile = Whi + (size_t)(bn * 224 + ks * TILES) * 4096;
  const unsigned short* wl_tile = Wlo + (size_t)(bn * 224 + ks * TILES) * 4096;

  f32x4 acc1[4][4], acc2[4][4];
  #pragma unroll
  for (int m = 0; m < 4; ++m)
    #pragma unroll
    for (int n = 0; n < 4; ++n) { acc1[m][n] = (f32x4)0.0f; acc2[m][n] = (f32x4)0.0f; }

  // fragment read byte offsets, fixed per lane
  int aro[4], bro[4];
  const int gi = lane >> 4;
  #pragma unroll
  for (int m = 0; m < 4; ++m) {
    const int row = wm * 64 + m * 16 + (lane & 15);
    aro[m] = row * 64 + swz(gi, row) * 16;
  }
  #pragma unroll
  for (int n = 0; n < 4; ++n) {
    const int row = wn * 64 + n * 16 + (lane & 15);
    bro[n] = row * 64 + swz(gi, row) * 16;
  }

  // ---- prologue: stage tile 0 into buf0; prefetch A(1) ----
  float4 pa[4], pb[4];
  {
    // glds first (oldest in vmcnt queue)
    #pragma unroll
    for (int i = 0; i < 2; ++i) {
      const int c = wid * 2 + i;          // chunk 0..7, wave-uniform
      glds16(wh_tile + c * 512 + lane * 8, lds + 16384 + c * 1024);
      glds16(wl_tile + c * 512 + lane * 8, lds + 24576 + c * 1024);
    }
    __builtin_amdgcn_sched_barrier(0);
    // A(0): load + convert + ds_write
    float4 a[4];
    #pragma unroll
    for (int i = 0; i < 4; ++i) a[i] = *(const float4*)(xsrc + i * 4);
    unsigned int hw[8], lw[8];
    #pragma unroll
    for (int q = 0; q < 8; ++q) {
      float f0 = ((const float*)a)[2 * q], f1 = ((const float*)a)[2 * q + 1];
      unsigned short h0 = f2h(f0), h1 = f2h(f1);
      unsigned short l0 = f2h((f0 - h2f(h0)) * 2048.0f);
      unsigned short l1 = f2h((f1 - h2f(h1)) * 2048.0f);
      hw[q] = (unsigned)h0 | ((unsigned)h1 << 16);
      lw[q] = (unsigned)l0 | ((unsigned)l1 << 16);
    }
    *(uint4*)(lds + aw0)        = make_uint4(hw[0], hw[1], hw[2], hw[3]);
    *(uint4*)(lds + aw1)        = make_uint4(hw[4], hw[5], hw[6], hw[7]);
    *(uint4*)(lds + 8192 + aw0) = make_uint4(lw[0], lw[1], lw[2], lw[3]);
    *(uint4*)(lds + 8192 + aw1) = make_uint4(lw[4], lw[5], lw[6], lw[7]);
    // prefetch A(1) (newest in queue)
    const int s1 = (TILES > 1) ? 1 : 0;
    #pragma unroll
    for (int i = 0; i < 4; ++i)
      pa[i] = *(const float4*)(xsrc + (size_t)s1 * 32 + i * 4);
    __builtin_amdgcn_sched_barrier(0);
  }
  asm volatile("s_waitcnt vmcnt(4) lgkmcnt(0)" ::: "memory");  // glds done, pa flying
  __builtin_amdgcn_sched_barrier(0);
  __builtin_amdgcn_s_barrier();

  int cur = 0;
  for (int s = 0; s < TILES; ++s) {
    const int nxt = cur ^ 1;
    char* base_c = lds + cur * 32768;
    char* base_n = lds + nxt * 32768;
    const bool stage_next = (s + 1 < TILES);

    // 1. issue glds B(s+1) (oldest vmem this tile)
    if (stage_next) {
      const unsigned short* wh = wh_tile + (size_t)(s + 1) * 4096;
      const unsigned short* wl = wl_tile + (size_t)(s + 1) * 4096;
      #pragma unroll
      for (int i = 0; i < 2; ++i) {
        const int c = wid * 2 + i;
        glds16(wh + c * 512 + lane * 8, base_n + 16384 + c * 1024);
        glds16(wl + c * 512 + lane * 8, base_n + 24576 + c * 1024);
      }
    }
    __builtin_amdgcn_sched_barrier(0);

    // 2. issue A(s+2) loads, clamped so exactly 4 are always in flight
    {
      int sn = s + 2; if (sn > TILES - 1) sn = TILES - 1;
      #pragma unroll
      for (int i = 0; i < 4; ++i)
        pb[i] = *(const float4*)(xsrc + (size_t)sn * 32 + i * 4);
    }
    __builtin_amdgcn_sched_barrier(0);

    // 3. compute from buf[cur]
    {
      const char* Ahi = base_c;          const char* Alo = base_c + 8192;
      const char* Bh  = base_c + 16384;  const char* Bl  = base_c + 24576;
      f16x8 ah[4], al[4], bh[4], bl[4];
      #pragma unroll
      for (int m = 0; m < 4; ++m) {
        ah[m] = *(const f16x8*)(Ahi + aro[m]);
        al[m] = *(const f16x8*)(Alo + aro[m]);
      }
      #pragma unroll
      for (int n = 0; n < 4; ++n) {
        bh[n] = *(const f16x8*)(Bh + bro[n]);
        bl[n] = *(const f16x8*)(Bl + bro[n]);
      }
      __builtin_amdgcn_s_setprio(1);
      #pragma unroll
      for (int m = 0; m < 4; ++m)
        #pragma unroll
        for (int n = 0; n < 4; ++n) {
          acc1[m][n] = __builtin_amdgcn_mfma_f32_16x16x32_f16(ah[m], bh[n], acc1[m][n], 0, 0, 0);
          acc2[m][n] = __builtin_amdgcn_mfma_f32_16x16x32_f16(ah[m], bl[n], acc2[m][n], 0, 0, 0);
          acc2[m][n] = __builtin_amdgcn_mfma_f32_16x16x32_f16(al[m], bh[n], acc2[m][n], 0, 0, 0);
        }
      __builtin_amdgcn_s_setprio(0);
    }

    // 4. convert + ds_write A(s+1) into buf[nxt]
    if (stage_next) {
      unsigned int hw[8], lw[8];
      #pragma unroll
      for (int q = 0; q < 8; ++q) {
        float f0 = ((const float*)pa)[2 * q], f1 = ((const float*)pa)[2 * q + 1];
        unsigned short h0 = f2h(f0), h1 = f2h(f1);
        unsigned short l0 = f2h((f0 - h2f(h0)) * 2048.0f);
        unsigned short l1 = f2h((f1 - h2f(h1)) * 2048.0f);
        hw[q] = (unsigned)h0 | ((unsigned)h1 << 16);
        lw[q] = (unsigned)l0 | ((unsigned)l1 << 16);
      }
      *(uint4*)(base_n + aw0)        = make_uint4(hw[0], hw[1], hw[2], hw[3]);
      *(uint4*)(base_n + aw1)        = make_uint4(hw[4], hw[5], hw[6], hw[7]);
      *(uint4*)(base_n + 8192 + aw0) = make_uint4(lw[0], lw[1], lw[2], lw[3]);
      *(uint4*)(base_n + 8192 + aw1) = make_uint4(lw[4], lw[5], lw[6], lw[7]);
    }
    #pragma unroll
    for (int i = 0; i < 4; ++i) pa[i] = pb[i];

    // 5. counted drain + raw barrier: glds(s+1) done, A(s+2) stays in flight
    asm volatile("s_waitcnt vmcnt(4) lgkmcnt(0)" ::: "memory");
    __builtin_amdgcn_sched_barrier(0);
    __builtin_amdgcn_s_barrier();

    cur = nxt;
  }

  // epilogue: logit partial = (acc1 + acc2/2048) / 64
  // C/D layout: col=lane&15, row=(lane>>4)*4+reg
  float* Sp = Spart + (size_t)ks * 8192 * 256;
  #pragma unroll
  for (int m = 0; m < 4; ++m)
    #pragma unroll
    for (int n = 0; n < 4; ++n)
      #pragma unroll
      for (int r = 0; r < 4; ++r) {
        const int t = TM + wm * 64 + m * 16 + (lane >> 4) * 4 + r;
        const int e = bn * 128 + wn * 64 + n * 16 + (lane & 15);
        Sp[(size_t)t * 256 + e] =
            (acc1[m][n][r] + acc2[m][n][r] * (1.0f / 2048.0f)) * (1.0f / 64.0f);
      }
}

// ---------------------------------------------------------------------------
// Routing: one wave per token. logit = sum of KS fp32 partials in DOUBLE
// (exact); scores = sigmoid (fp32); then grouped top-k (8 groups, top-2
// group score, top-4 groups, top-8 experts, renorm * 2.5).
// ---------------------------------------------------------------------------
__global__ __launch_bounds__(256) void gate_routing(
    const float* __restrict__ Spart, int KS,
    const float* __restrict__ bias,
    float* __restrict__ outw, float* __restrict__ outi, int T)
{
  const int lane = threadIdx.x & 63;
  const int wave = threadIdx.x >> 6;
  const int t = blockIdx.x * 4 + wave;
  if (t >= T) return;

  double l[4] = {0.0, 0.0, 0.0, 0.0};
  for (int ks = 0; ks < KS; ++ks) {
    float4 p = *(const float4*)(Spart + (size_t)ks * T * 256
                                + (size_t)t * 256 + lane * 4);
    l[0] += (double)p.x; l[1] += (double)p.y;
    l[2] += (double)p.z; l[3] += (double)p.w;
  }

  float4 bi = *(const float4*)(bias + lane * 4);
  float orig[4], s[4];
  #pragma unroll
  for (int u = 0; u < 4; ++u)
    orig[u] = 1.0f / (1.0f + expf(-(float)l[u]));
  s[0] = orig[0] + bi.x; s[1] = orig[1] + bi.y;
  s[2] = orig[2] + bi.z; s[3] = orig[3] + bi.w;

  // per-lane top-2 of its 4 biased scores
  float m1 = -INFINITY, m2 = -INFINITY;
  #pragma unroll
  for (int u = 0; u < 4; ++u) {
    float v = s[u];
    if (v > m1) { m2 = m1; m1 = v; }
    else if (v > m2) { m2 = v; }
  }
  // merge top-2 across the 8 lanes of the group
  #pragma unroll
  for (int off = 1; off < 8; off <<= 1) {
    float o1 = __shfl_xor(m1, off, 64);
    float o2 = __shfl_xor(m2, off, 64);
    if (o1 > m1) { m2 = fmaxf(m1, o2); m1 = o1; }
    else         { m2 = fmaxf(m2, o1); }
  }
  const float gscore = m1 + m2;

  const int g = lane >> 3;
  int rank = 0;
  #pragma unroll
  for (int j = 0; j < 8; ++j) {
    float gs = __shfl(gscore, j * 8, 64);
    rank += (gs > gscore || (gs == gscore && j < g)) ? 1 : 0;
  }
  if (rank >= 4) { s[0] = s[1] = s[2] = s[3] = -INFINITY; }

  float wsum = 0.0f, sel_w = 0.0f;
  int sel_i = 0;
  #pragma unroll
  for (int it = 0; it < 8; ++it) {
    float bv = s[0]; int bu = 0;
    #pragma unroll
    for (int u = 1; u < 4; ++u)
      if (s[u] > bv) { bv = s[u]; bu = u; }
    float v = bv;
    int ix = lane * 4 + bu;
    float og = orig[bu];
    #pragma unroll
    for (int off = 1; off < 64; off <<= 1) {
      float ov  = __shfl_xor(v,  off, 64);
      int   oix = __shfl_xor(ix, off, 64);
      float oog = __shfl_xor(og, off, 64);
      if (ov > v || (ov == v && oix < ix)) { v = ov; ix = oix; og = oog; }
    }
    if (lane == it) { sel_w = og; sel_i = ix; }
    wsum += og;
    if ((ix >> 2) == lane) s[ix & 3] = -INFINITY;
  }

  if (lane < 8) {
    outw[(size_t)t * 8 + lane] = sel_w / wsum * 2.5f;
    outi[(size_t)t * 8 + lane] = (float)sel_i;
  }
}

extern "C" void kernel_launch(void* const* d_in, const int* in_sizes, int n_in,
                              void* d_out, int out_size, void* d_ws, size_t ws_size,
                              hipStream_t stream) {
  const float* x = (const float*)d_in[0];
  const float* w = (const float*)d_in[1];
  const float* b = (const float*)d_in[2];
  const int E = in_sizes[2];                  // 256
  const int D = in_sizes[1] / E;              // 7168
  const int T = in_sizes[0] / D;              // 8192

  unsigned short* Whi = (unsigned short*)d_ws;                       // 3.67 MB
  unsigned short* Wlo = (unsigned short*)((char*)d_ws + (4u << 20)); // 3.67 MB
  float* Spart = (float*)((char*)d_ws + (8u << 20));                 // KS x 8 MB

  // adaptive K-split: largest of {8,4,2} that fits the workspace
  const size_t per_part = (size_t)T * E * 4;
  int KS = 2;
  if (ws_size >= (8u << 20) + 8 * per_part) KS = 8;
  else if (ws_size >= (8u << 20) + 4 * per_part) KS = 4;
  const int TILES = D / (32 * KS);            // 28 for KS=8

  float* outw = (float*)d_out;
  float* outi = outw + (size_t)T * 8;

  convert_w<<<E, 256, 0, stream>>>(w, Whi, Wlo);
  // 1-D grid, ks fastest (XCD-affine for KS=8): 2*KS*(T/128) blocks
  gate_gemm<<<2 * KS * (T / 128), 256, 0, stream>>>(x, Whi, Wlo, Spart, D, TILES, KS);
  gate_routing<<<(T + 3) / 4, 256, 0, stream>>>(Spart, KS, b, outw, outi, T);
}